// Round 1
// baseline (5410.743 us; speedup 1.0000x reference)
//
#include <hip/hip_runtime.h>
#include <hip/hip_bf16.h>

namespace {

constexpr int kB  = 256;   // batch
constexpr int kP  = 256;   // proposals
constexpr int kT  = 32;    // words
constexpr int kNS = 31;    // steps = T-1
constexpr int kV  = 3433;  // vocab
constexpr int kH  = 512;   // hidden
constexpr int kE  = 300;   // embed
constexpr int kC  = 128;   // feat dim
constexpr int kG  = 1536;  // 3H

__device__ __forceinline__ float fexp2(float x) {
  float r; asm("v_exp_f32 %0, %1" : "=v"(r) : "v"(x)); return r;
}
__device__ __forceinline__ float frcp(float x) {
  float r; asm("v_rcp_f32 %0, %1" : "=v"(r) : "v"(x)); return r;
}
// tanh(x) = 1 - 2/(exp(2x)+1), exact at +-inf, ~1ulp-ish accuracy
__device__ __forceinline__ float ftanh(float x) {
  float e = fexp2(x * 2.8853900817779268f);   // exp2(2x*log2e) = e^(2x)
  return 1.0f - 2.0f * frcp(e + 1.0f);
}
__device__ __forceinline__ float fsigm(float x) {
  return frcp(1.0f + fexp2(x * -1.4426950408889634f));
}
__device__ __forceinline__ unsigned short f2bf(float f) {   // RNE bf16
  unsigned u = __float_as_uint(f);
  u += 0x7FFFu + ((u >> 16) & 1u);
  return (unsigned short)(u >> 16);
}

// ---------------- one-time weight transposes (W[r][k] -> Wt[k*R + r]) -------
__global__ void k_transpose(const float* s0, const float* s1, const float* s2,
                            const float* s3, const float* s4, const float* s5,
                            const float* s6, const float* s7,
                            float* d0, float* d1, float* d2, float* d3,
                            float* d4, float* d5, float* d6, float* d7) {
  const float* src; float* dst; int R, Cd;
  switch (blockIdx.y) {
    case 0:  src = s0; dst = d0; R = 128;  Cd = 300; break;  // W_td3
    case 1:  src = s1; dst = d1; R = 128;  Cd = 512; break;  // W_td1
    case 2:  src = s2; dst = d2; R = 128;  Cd = 128; break;  // W_td
    case 3:  src = s3; dst = d3; R = 128;  Cd = 128; break;  // W_l1
    case 4:  src = s4; dst = d4; R = 128;  Cd = 512; break;  // W_l2
    case 5:  src = s5; dst = d5; R = 128;  Cd = 128; break;  // W_l
    case 6:  src = s6; dst = d6; R = 1536; Cd = 128; break;  // W1_ih
    default: src = s7; dst = d7; R = 1536; Cd = 128; break;  // W2_ih
  }
  int n = R * Cd;
  for (int i = blockIdx.x * blockDim.x + threadIdx.x; i < n;
       i += gridDim.x * blockDim.x) {
    int k = i / R, r = i - k * R;
    dst[i] = src[r * Cd + k];    // dst[k*R + r]
  }
}

// ---------------- init: td = t_feat @ W_td2^T ; zero h1,h2 -------------------
__global__ void k_init(const float* __restrict__ t_feat,
                       const float* __restrict__ W_td2,
                       float* __restrict__ td, float* __restrict__ h1,
                       float* __restrict__ h2) {
  int tid = blockIdx.x * 256 + threadIdx.x;  // 32768 threads
  int b = tid >> 7, c = tid & 127;
  const float* tf = t_feat + b * kC;
  const float* w  = W_td2 + c * kC;
  float acc = 0.f;
  for (int k = 0; k < kC; ++k) acc = fmaf(tf[k], w[k], acc);
  td[tid] = acc;
  for (int i = tid; i < kB * kH; i += (1 << 15)) { h1[i] = 0.f; h2[i] = 0.f; }
}

// ---------------- shared 64x64 NT-GEMM tile body -----------------------------
// C[m,n] = sum_k A[m*K+k]*Bw[n*K+k]; A/B staged LDS transposed [kk][row].
__device__ __forceinline__ void gemm64body(
    const float* __restrict__ A, const float* __restrict__ Bw,
    int bRowMax, int m0, int n0, int KDIM,
    float acc[4][4], float (*As)[68], float (*Bs)[68]) {
  int tid = threadIdx.x;
  int lr = tid >> 2, lq = (tid & 3) << 3;   // loader: row, k-offset
  int tn = tid & 15, tm = tid >> 4;         // compute: n fast -> coalesced C
  for (int k0 = 0; k0 < KDIM; k0 += 32) {
    int br = n0 + lr; if (br > bRowMax) br = bRowMax;
    const float* pa = A + (size_t)(m0 + lr) * KDIM + k0 + lq;
    const float* pb = Bw + (size_t)br * KDIM + k0 + lq;
    float4 a0 = *(const float4*)pa;
    float4 a1 = *(const float4*)(pa + 4);
    float4 b0 = *(const float4*)pb;
    float4 b1 = *(const float4*)(pb + 4);
    __syncthreads();   // previous compute done before overwriting tiles
    As[lq + 0][lr] = a0.x; As[lq + 1][lr] = a0.y;
    As[lq + 2][lr] = a0.z; As[lq + 3][lr] = a0.w;
    As[lq + 4][lr] = a1.x; As[lq + 5][lr] = a1.y;
    As[lq + 6][lr] = a1.z; As[lq + 7][lr] = a1.w;
    Bs[lq + 0][lr] = b0.x; Bs[lq + 1][lr] = b0.y;
    Bs[lq + 2][lr] = b0.z; Bs[lq + 3][lr] = b0.w;
    Bs[lq + 4][lr] = b1.x; Bs[lq + 5][lr] = b1.y;
    Bs[lq + 6][lr] = b1.z; Bs[lq + 7][lr] = b1.w;
    __syncthreads();
    #pragma unroll
    for (int kk = 0; kk < 32; ++kk) {
      float4 af = *(const float4*)&As[kk][tm * 4];
      float4 bf = *(const float4*)&Bs[kk][tn * 4];
      float av[4] = {af.x, af.y, af.z, af.w};
      float bv[4] = {bf.x, bf.y, bf.z, bf.w};
      #pragma unroll
      for (int i = 0; i < 4; ++i)
        #pragma unroll
        for (int j = 0; j < 4; ++j)
          acc[i][j] = fmaf(av[i], bv[j], acc[i][j]);
    }
  }
}

// ---------------- feat_proj = c_feats @ W_feat^T -> bf16 ---------------------
__global__ __launch_bounds__(256) void k_featproj(
    const float* __restrict__ A, const float* __restrict__ Bw,
    unsigned short* __restrict__ out) {
  __shared__ float As[32][68];
  __shared__ float Bs[32][68];
  int m0 = blockIdx.x * 64, n0 = blockIdx.y * 64;
  float acc[4][4] = {};
  gemm64body(A, Bw, kH - 1, m0, n0, kC, acc, As, Bs);
  int tid = threadIdx.x;
  int tn = tid & 15, tm = tid >> 4;
  #pragma unroll
  for (int i = 0; i < 4; ++i) {
    int m = m0 + tm * 4 + i;
    ushort4 o;
    o.x = f2bf(acc[i][0]); o.y = f2bf(acc[i][1]);
    o.z = f2bf(acc[i][2]); o.w = f2bf(acc[i][3]);
    *(ushort4*)(out + (size_t)m * kH + n0 + tn * 4) = o;
  }
}

// ---------------- stage A: [s-chain blocks] + [gh1 GEMM] + [gh2 GEMM] --------
__global__ __launch_bounds__(256) void k_stageA(
    const float* __restrict__ word_embs, int t,
    const float* __restrict__ h1, const float* __restrict__ h2,
    const float* __restrict__ td,
    const float* __restrict__ td3t, const float* __restrict__ td1t,
    const float* __restrict__ tdt,
    const float* __restrict__ W1_hh, const float* __restrict__ b1_hh,
    const float* __restrict__ W2_hh, const float* __restrict__ b2_hh,
    float* __restrict__ sbuf, float* __restrict__ gh1,
    float* __restrict__ gh2) {
  __shared__ float smem[4352];
  int blk = blockIdx.x, tid = threadIdx.x;
  if (blk < 64) {
    // s = relu(tanh(x@W_td3^T + h2@W_td1^T + td) @ W_td^T), 4 batch rows/block
    float* xl  = smem;          // [4][300]
    float* h2l = smem + 1200;   // [4][512]
    float* tdl = smem + 3248;   // [4][128]
    float* s0t = smem + 3760;   // [4][128]
    int b0 = blk * 4;
    for (int r = 0; r < 4; ++r) {
      const float* xs = word_embs + (size_t)(b0 + r) * (kT * kE) + (size_t)t * kE;
      for (int e = tid; e < kE; e += 256) xl[r * kE + e] = xs[e];
      for (int k = tid; k < kH; k += 256) h2l[r * kH + k] = h2[(b0 + r) * kH + k];
    }
    for (int i = tid; i < 512; i += 256) tdl[i] = td[b0 * kC + i];
    __syncthreads();
    #pragma unroll
    for (int q = 0; q < 2; ++q) {
      int idx = tid + q * 256;
      int r = idx >> 7, c = idx & 127;
      float acc = tdl[r * kC + c];
      const float* xr = xl + r * kE;
      const float* w3 = td3t + c;
      for (int e = 0; e < kE; ++e) acc = fmaf(xr[e], w3[(size_t)e * 128], acc);
      const float* hr = h2l + r * kH;
      const float* w1 = td1t + c;
      for (int k = 0; k < kH; ++k) acc = fmaf(hr[k], w1[(size_t)k * 128], acc);
      s0t[idx] = ftanh(acc);
    }
    __syncthreads();
    #pragma unroll
    for (int q = 0; q < 2; ++q) {
      int idx = tid + q * 256;
      int r = idx >> 7, c = idx & 127;
      float acc = 0.f;
      const float* sr = s0t + r * kC;
      const float* w = tdt + c;
      for (int k = 0; k < kC; ++k) acc = fmaf(sr[k], w[k * 128], acc);
      sbuf[(b0 + r) * kC + c] = fmaxf(acc, 0.f);
    }
  } else {
    // gh = h @ W_hh^T + b_hh  (256x1536, K=512), 64x64 tiles
    int g = blk - 64;
    const float* A; const float* W; const float* bias; float* out;
    if (g < 96) { A = h1; W = W1_hh; bias = b1_hh; out = gh1; }
    else        { g -= 96; A = h2; W = W2_hh; bias = b2_hh; out = gh2; }
    int bi = g / 24, ji = g - bi * 24;
    int m0 = bi * 64, n0 = ji * 64;
    float (*As)[68] = (float(*)[68])smem;
    float (*Bs)[68] = (float(*)[68])(smem + 2176);
    float acc[4][4] = {};
    gemm64body(A, W, kG - 1, m0, n0, kH, acc, As, Bs);
    int tn = tid & 15, tm = tid >> 4;
    float4 bv = *(const float4*)(bias + n0 + tn * 4);
    #pragma unroll
    for (int i = 0; i < 4; ++i) {
      int row = m0 + tm * 4 + i;
      float4 o = make_float4(acc[i][0] + bv.x, acc[i][1] + bv.y,
                             acc[i][2] + bv.z, acc[i][3] + bv.w);
      *(float4*)(out + (size_t)row * kG + n0 + tn * 4) = o;
    }
  }
}

// ---------------- GRU1: gx1 = s@W1_ih^T + b ; combine -> h1 ------------------
__global__ __launch_bounds__(256) void k_gru1(
    const float* __restrict__ s, const float* __restrict__ W1_iht,
    const float* __restrict__ b1_ih, const float* __restrict__ gh,
    float* __restrict__ h1) {
  int bt = blockIdx.x >> 4, jt = blockIdx.x & 15;
  int b0 = bt * 32, j0 = jt * 32;
  int tid = threadIdx.x;
  int tj = tid & 31, tb = tid >> 5;
  int col = j0 + tj;
  float ar[4] = {}, az[4] = {}, an[4] = {};
  const float* srow = s + (size_t)(b0 + tb * 4) * kC;
  for (int kk = 0; kk < kC; kk += 4) {
    float4 s0 = *(const float4*)(srow + kk);
    float4 s1 = *(const float4*)(srow + kC + kk);
    float4 s2 = *(const float4*)(srow + 2 * kC + kk);
    float4 s3 = *(const float4*)(srow + 3 * kC + kk);
    float sv[4][4] = {{s0.x, s0.y, s0.z, s0.w}, {s1.x, s1.y, s1.z, s1.w},
                      {s2.x, s2.y, s2.z, s2.w}, {s3.x, s3.y, s3.z, s3.w}};
    #pragma unroll
    for (int q = 0; q < 4; ++q) {
      float wr = W1_iht[(size_t)(kk + q) * kG + col];
      float wz = W1_iht[(size_t)(kk + q) * kG + 512 + col];
      float wn = W1_iht[(size_t)(kk + q) * kG + 1024 + col];
      #pragma unroll
      for (int i = 0; i < 4; ++i) {
        ar[i] = fmaf(sv[i][q], wr, ar[i]);
        az[i] = fmaf(sv[i][q], wz, az[i]);
        an[i] = fmaf(sv[i][q], wn, an[i]);
      }
    }
  }
  float bir = b1_ih[col], biz = b1_ih[512 + col], bn = b1_ih[1024 + col];
  #pragma unroll
  for (int i = 0; i < 4; ++i) {
    int b = b0 + tb * 4 + i;
    float ghr = gh[(size_t)b * kG + col];
    float ghz = gh[(size_t)b * kG + 512 + col];
    float ghn = gh[(size_t)b * kG + 1024 + col];
    float rr = fsigm(ar[i] + bir + ghr);
    float zz = fsigm(az[i] + biz + ghz);
    float nn = ftanh(an[i] + bn + rr * ghn);
    float ho = h1[(size_t)b * kH + col];
    h1[(size_t)b * kH + col] = (1.f - zz) * nn + zz * ho;
  }
}

// ---------------- hq = h1 @ W_hidd^T (256x512, K=512), 32x64 tiles -----------
__global__ __launch_bounds__(256) void k_hq(
    const float* __restrict__ h1, const float* __restrict__ W_hidd,
    float* __restrict__ hq) {
  __shared__ float As[32][36];
  __shared__ float Bs[32][68];
  int m0 = blockIdx.x * 32, n0 = blockIdx.y * 64;
  int tid = threadIdx.x;
  int ar = tid >> 3, aq = (tid & 7) * 4;
  int lr = tid >> 2, lq = (tid & 3) * 8;
  int tn = tid & 15, tm = tid >> 4;
  float acc[2][4] = {};
  for (int k0 = 0; k0 < kH; k0 += 32) {
    float4 av = *(const float4*)(h1 + (size_t)(m0 + ar) * kH + k0 + aq);
    const float* pb = W_hidd + (size_t)(n0 + lr) * kH + k0 + lq;
    float4 b0v = *(const float4*)pb;
    float4 b1v = *(const float4*)(pb + 4);
    __syncthreads();
    As[aq + 0][ar] = av.x; As[aq + 1][ar] = av.y;
    As[aq + 2][ar] = av.z; As[aq + 3][ar] = av.w;
    Bs[lq + 0][lr] = b0v.x; Bs[lq + 1][lr] = b0v.y;
    Bs[lq + 2][lr] = b0v.z; Bs[lq + 3][lr] = b0v.w;
    Bs[lq + 4][lr] = b1v.x; Bs[lq + 5][lr] = b1v.y;
    Bs[lq + 6][lr] = b1v.z; Bs[lq + 7][lr] = b1v.w;
    __syncthreads();
    #pragma unroll
    for (int kk = 0; kk < 32; ++kk) {
      float2 a2 = *(const float2*)&As[kk][tm * 2];
      float4 b4 = *(const float4*)&Bs[kk][tn * 4];
      acc[0][0] = fmaf(a2.x, b4.x, acc[0][0]);
      acc[0][1] = fmaf(a2.x, b4.y, acc[0][1]);
      acc[0][2] = fmaf(a2.x, b4.z, acc[0][2]);
      acc[0][3] = fmaf(a2.x, b4.w, acc[0][3]);
      acc[1][0] = fmaf(a2.y, b4.x, acc[1][0]);
      acc[1][1] = fmaf(a2.y, b4.y, acc[1][1]);
      acc[1][2] = fmaf(a2.y, b4.z, acc[1][2]);
      acc[1][3] = fmaf(a2.y, b4.w, acc[1][3]);
    }
  }
  #pragma unroll
  for (int i = 0; i < 2; ++i) {
    int row = m0 + tm * 2 + i;
    *(float4*)(hq + (size_t)row * kH + n0 + tn * 4) =
        make_float4(acc[i][0], acc[i][1], acc[i][2], acc[i][3]);
  }
}

// ---------------- attention: scores/softmax/attended per batch row -----------
__global__ __launch_bounds__(512) void k_attn(
    const float* __restrict__ hqb, const float* __restrict__ W_att,
    const unsigned short* __restrict__ fp, const float* __restrict__ c_feats,
    float* __restrict__ att, float* __restrict__ attn_out, int t) {
  int b = blockIdx.x, tid = threadIdx.x;
  int lane = tid & 63, wv = tid >> 6;   // 8 waves
  __shared__ float scs[256];
  __shared__ float red[8];
  __shared__ float red2[8];
  __shared__ float part[4][128];
  float hql[8], aw[8];
  {
    float4 h0 = *(const float4*)(hqb + b * kH + lane * 8);
    float4 h1v = *(const float4*)(hqb + b * kH + lane * 8 + 4);
    hql[0] = h0.x; hql[1] = h0.y; hql[2] = h0.z; hql[3] = h0.w;
    hql[4] = h1v.x; hql[5] = h1v.y; hql[6] = h1v.z; hql[7] = h1v.w;
    float4 a0 = *(const float4*)(W_att + lane * 8);
    float4 a1 = *(const float4*)(W_att + lane * 8 + 4);
    aw[0] = a0.x; aw[1] = a0.y; aw[2] = a0.z; aw[3] = a0.w;
    aw[4] = a1.x; aw[5] = a1.y; aw[6] = a1.z; aw[7] = a1.w;
  }
  const unsigned short* fpb = fp + (size_t)b * kP * kH;
  for (int p = wv * 32; p < wv * 32 + 32; ++p) {
    uint4 rv = *(const uint4*)(fpb + (size_t)p * kH + lane * 8);
    union { uint4 v; unsigned short s[8]; } u; u.v = rv;
    float sc = 0.f;
    #pragma unroll
    for (int j = 0; j < 8; ++j) {
      float f = __uint_as_float((unsigned)u.s[j] << 16);
      sc += aw[j] * ftanh(f + hql[j]);
    }
    #pragma unroll
    for (int m = 32; m; m >>= 1) sc += __shfl_xor(sc, m, 64);
    if (lane == 0) scs[p] = sc;
  }
  __syncthreads();
  // softmax over 256 proposals
  float sv = (tid < 256) ? scs[tid] : -1e30f;
  float mx = sv;
  #pragma unroll
  for (int m = 32; m; m >>= 1) mx = fmaxf(mx, __shfl_xor(mx, m, 64));
  if (lane == 0) red[wv] = mx;
  __syncthreads();
  float bm = red[0];
  #pragma unroll
  for (int i = 1; i < 8; ++i) bm = fmaxf(bm, red[i]);
  float ev = (tid < 256) ? fexp2((sv - bm) * 1.4426950408889634f) : 0.f;
  float sm = ev;
  #pragma unroll
  for (int m = 32; m; m >>= 1) sm += __shfl_xor(sm, m, 64);
  if (lane == 0) red2[wv] = sm;
  __syncthreads();
  float tot = red2[0] + red2[1] + red2[2] + red2[3] +
              red2[4] + red2[5] + red2[6] + red2[7];
  float inv = frcp(tot);
  if (tid < 256) {
    float mk = ev * inv;
    scs[tid] = mk;   // reuse as mask
    attn_out[(size_t)b * kP * kNS + (size_t)tid * kNS + t] = mk;
  }
  __syncthreads();
  // attended = sum_p mask[p] * c_feats[b,p,:]
  {
    int c = tid & 127, q = tid >> 7;   // q in 0..3, 64 proposals each
    const float* cf = c_feats + ((size_t)b * kP + q * 64) * kC + c;
    float acc = 0.f;
    for (int p = 0; p < 64; ++p) acc = fmaf(scs[q * 64 + p], cf[(size_t)p * kC], acc);
    part[q][c] = acc;
  }
  __syncthreads();
  if (tid < 128)
    att[b * kC + tid] = part[0][tid] + part[1][tid] + part[2][tid] + part[3][tid];
}

// ---------------- language chain + GRU2 combine + h2_all ---------------------
__global__ __launch_bounds__(256) void k_lang(
    const float* __restrict__ att, const float* __restrict__ h1,
    const float* __restrict__ W_l1t, const float* __restrict__ W_l2t,
    const float* __restrict__ W_lt, const float* __restrict__ W2_iht,
    const float* __restrict__ b2_ih, const float* __restrict__ gh2,
    float* __restrict__ h2, float* __restrict__ h2all, int t) {
  __shared__ float attl[2 * 128];
  __shared__ float h1l[2 * 512];
  __shared__ float h2l[2 * 512];
  __shared__ float ltl[2 * 128];
  __shared__ float ll[2 * 128];
  __shared__ float gxt[2 * 1536];
  int b0 = blockIdx.x * 2;
  int tid = threadIdx.x;
  attl[tid] = att[b0 * 128 + tid];
  for (int i = tid; i < 1024; i += 256) {
    h1l[i] = h1[b0 * 512 + i];
    h2l[i] = h2[b0 * 512 + i];
  }
  __syncthreads();
  {
    int r = tid >> 7, c = tid & 127;
    float acc = 0.f;
    const float* a = attl + r * 128;
    const float* w1 = W_l1t + c;
    for (int k = 0; k < 128; ++k) acc = fmaf(a[k], w1[k * 128], acc);
    const float* hr = h1l + r * 512;
    const float* w2 = W_l2t + c;
    for (int k = 0; k < 512; ++k) acc = fmaf(hr[k], w2[(size_t)k * 128], acc);
    ltl[tid] = ftanh(acc);
  }
  __syncthreads();
  {
    int r = tid >> 7, c = tid & 127;
    float acc = 0.f;
    const float* lr_ = ltl + r * 128;
    const float* w = W_lt + c;
    for (int k = 0; k < 128; ++k) acc = fmaf(lr_[k], w[k * 128], acc);
    ll[tid] = fmaxf(acc, 0.f);
  }
  __syncthreads();
  for (int r = 0; r < 2; ++r) {
    const float* lr_ = ll + r * 128;
    for (int q = 0; q < 6; ++q) {
      int jj = tid + q * 256;
      float acc = b2_ih[jj];
      const float* w = W2_iht + jj;
      for (int k = 0; k < 128; ++k) acc = fmaf(lr_[k], w[(size_t)k * kG], acc);
      gxt[r * kG + jj] = acc;
    }
  }
  __syncthreads();
  for (int q = 0; q < 4; ++q) {
    int idx = tid + q * 256;
    int r = idx >> 9, jv = idx & 511;
    int b = b0 + r;
    float gr = gxt[r * kG + jv];
    float gz = gxt[r * kG + 512 + jv];
    float gn = gxt[r * kG + 1024 + jv];
    float ghr = gh2[(size_t)b * kG + jv];
    float ghz = gh2[(size_t)b * kG + 512 + jv];
    float ghn = gh2[(size_t)b * kG + 1024 + jv];
    float ho = h2l[r * 512 + jv];
    float rr = fsigm(gr + ghr);
    float zz = fsigm(gz + ghz);
    float nn = ftanh(gn + rr * ghn);
    float hn = (1.f - zz) * nn + zz * ho;
    h2[(size_t)b * kH + jv] = hn;
    h2all[((size_t)t * kB + b) * kH + jv] = hn;
  }
}

// ---------------- classifier: lang = h2_all @ W_cls^T + b_cls ----------------
__global__ __launch_bounds__(256) void k_cls(
    const float* __restrict__ A, const float* __restrict__ Wc,
    const float* __restrict__ bc, float* __restrict__ out) {
  __shared__ float As[32][68];
  __shared__ float Bs[32][68];
  int m0 = blockIdx.x * 64, n0 = blockIdx.y * 64;
  float acc[4][4] = {};
  gemm64body(A, Wc, kV - 1, m0, n0, kH, acc, As, Bs);
  int tid = threadIdx.x;
  int tn = tid & 15, tm = tid >> 4;
  #pragma unroll
  for (int i = 0; i < 4; ++i) {
    int m = m0 + tm * 4 + i;
    int tt = m >> 8, b = m & 255;
    float* orow = out + (size_t)b * (kNS * kV) + (size_t)tt * kV;
    #pragma unroll
    for (int j = 0; j < 4; ++j) {
      int col = n0 + tn * 4 + j;
      if (col < kV) orow[col] = acc[i][j] + bc[col];
    }
  }
}

}  // namespace

extern "C" void kernel_launch(void* const* d_in, const int* in_sizes, int n_in,
                              void* d_out, int out_size, void* d_ws,
                              size_t ws_size, hipStream_t stream) {
  (void)in_sizes; (void)n_in; (void)out_size; (void)ws_size;
  const float* word_embs = (const float*)d_in[0];
  const float* t_feat    = (const float*)d_in[1];
  const float* c_feats   = (const float*)d_in[2];
  // d_in[3] = num_words (static 32 -> 31 steps)
  const float* W_td1 = (const float*)d_in[4];
  const float* W_td2 = (const float*)d_in[5];
  const float* W_td3 = (const float*)d_in[6];
  const float* W_td  = (const float*)d_in[7];
  const float* W1_ih = (const float*)d_in[8];
  const float* W1_hh = (const float*)d_in[9];
  const float* b1_ih = (const float*)d_in[10];
  const float* b1_hh = (const float*)d_in[11];
  const float* W_feat = (const float*)d_in[12];
  const float* W_hidd = (const float*)d_in[13];
  const float* W_att  = (const float*)d_in[14];
  const float* W_l1 = (const float*)d_in[15];
  const float* W_l2 = (const float*)d_in[16];
  const float* W_l  = (const float*)d_in[17];
  const float* W2_ih = (const float*)d_in[18];
  const float* W2_hh = (const float*)d_in[19];
  const float* b2_ih = (const float*)d_in[20];
  const float* b2_hh = (const float*)d_in[21];
  const float* W_cls = (const float*)d_in[22];
  const float* b_cls = (const float*)d_in[23];

  float* lang = (float*)d_out;
  float* attn_out = lang + (size_t)kB * kNS * kV;
  // feat_proj (bf16, 64MB) lives in the lang_cap region of d_out — it is dead
  // by the time k_cls (the only writer of lang_cap) runs.
  unsigned short* fp = (unsigned short*)d_out;

  float* p = (float*)d_ws;
  float* h1 = p;      p += kB * kH;
  float* h2 = p;      p += kB * kH;
  float* td = p;      p += kB * kC;
  float* sbuf = p;    p += kB * kC;
  float* att = p;     p += kB * kC;
  float* hqb = p;     p += kB * kH;
  float* gh1 = p;     p += (size_t)kB * kG;
  float* gh2 = p;     p += (size_t)kB * kG;
  float* h2all = p;   p += (size_t)kNS * kB * kH;
  float* td3t = p;    p += kE * 128;
  float* td1t = p;    p += kH * 128;
  float* tdt  = p;    p += 128 * 128;
  float* l1t  = p;    p += 128 * 128;
  float* l2t  = p;    p += kH * 128;
  float* lt   = p;    p += 128 * 128;
  float* iht1 = p;    p += 128 * kG;
  float* iht2 = p;    p += 128 * kG;

  k_transpose<<<dim3(64, 8), 256, 0, stream>>>(
      W_td3, W_td1, W_td, W_l1, W_l2, W_l, W1_ih, W2_ih,
      td3t, td1t, tdt, l1t, l2t, lt, iht1, iht2);
  k_init<<<128, 256, 0, stream>>>(t_feat, W_td2, td, h1, h2);
  k_featproj<<<dim3(1024, 8), 256, 0, stream>>>(c_feats, W_feat, fp);
  for (int t = 0; t < kNS; ++t) {
    k_stageA<<<256, 256, 0, stream>>>(word_embs, t, h1, h2, td, td3t, td1t,
                                      tdt, W1_hh, b1_hh, W2_hh, b2_hh,
                                      sbuf, gh1, gh2);
    k_gru1<<<128, 256, 0, stream>>>(sbuf, iht1, b1_ih, gh1, h1);
    k_hq<<<dim3(8, 8), 256, 0, stream>>>(h1, W_hidd, hqb);
    k_attn<<<256, 512, 0, stream>>>(hqb, W_att, fp, c_feats, att, attn_out, t);
    k_lang<<<128, 256, 0, stream>>>(att, h1, l1t, l2t, lt, iht2, b2_ih, gh2,
                                    h2, h2all, t);
  }
  k_cls<<<dim3(124, 54), 256, 0, stream>>>(h2all, W_cls, b_cls, lang);
}